// Round 15
// baseline (77.145 us; speedup 1.0000x reference)
//
#include <hip/hip_runtime.h>
#include <hip/hip_bf16.h>

#define NAG 8
#define BATCH 32768
#define DDIM 128
#define ADIM 64
#define HDIM 128

#define NJ1 11            // layer1 col tiles: 128 (W1) + 32 (Wc1) + 1 (Ws1) -> 176 cols
#define NJ2 8
#define NJ3 4
#define FB_L1 (NJ1*4)     // 44 frag blocks (44KB)
#define FB_L2 (NJ2*4)     // 32
#define FB_L3 (NJ3*4)     // 16
#define FB_TOT (FB_L1+FB_L2+FB_L3)  // 92
#define WAGENT (FB_TOT*512)         // 47104 ushort per agent (92KB)

typedef __attribute__((ext_vector_type(8))) short bf16x8;
typedef __attribute__((ext_vector_type(4))) float f32x4;
typedef __attribute__((ext_vector_type(4))) unsigned int u32x4;

static __device__ __forceinline__ unsigned short f2bf(float f) {
  unsigned int u = __builtin_bit_cast(unsigned int, f);
  u += 0x7fffu + ((u >> 16) & 1u);          // RNE (inputs are finite)
  return (unsigned short)(u >> 16);
}

static __device__ __forceinline__ unsigned int cvt_pk_bf16(float a, float b) {
  unsigned int r;
  asm("v_cvt_pk_bf16_f32 %0, %1, %2" : "=v"(r) : "v"(a), "v"(b));
  return r;
}

// single-value f32->bf16 via one cvt_pk op (RNE), low 16 bits valid
static __device__ __forceinline__ unsigned short f2bf1(float f) {
  unsigned int r;
  asm("v_cvt_pk_bf16_f32 %0, %1, %2" : "=v"(r) : "v"(f), "v"(f));
  return (unsigned short)r;
}

// async global->LDS, 16B per lane; LDS dest = uniform base + lane*16 (linear)
static __device__ __forceinline__ void gload_lds16(const void* g, void* l) {
  __builtin_amdgcn_global_load_lds(
      (const __attribute__((address_space(1))) unsigned int*)g,
      (__attribute__((address_space(3))) unsigned int*)l, 16, 0, 0);
}

// ---------------- prep: f32 weights -> bf16 B-fragment-linear layout (proven) ----------------
// frag block fb=(j,kk): 512 bf16; element l*8+t = W[k = kk*32 + (l>>4)*8 + t][col = j*16 + (l&15)]
__global__ void __launch_bounds__(256)
prep_weights(const float* __restrict__ W1, const float* __restrict__ W2,
             const float* __restrict__ W3, const float* __restrict__ Wc1,
             const float* __restrict__ Ws1, const float* __restrict__ b1,
             const float* __restrict__ bc1, const float* __restrict__ bs1,
             unsigned short* __restrict__ wbuf, float* __restrict__ b1e)
{
  int tid = blockIdx.x * 256 + threadIdx.x;
  if (tid < NAG * WAGENT) {
    int agent = tid / WAGENT;
    int rem   = tid % WAGENT;
    int fb = rem >> 9;
    int li = rem & 511;
    int l = li >> 3, t = li & 7;
    int lr = l & 15, lg = l >> 4;
    float v = 0.0f;
    if (fb < FB_L1) {
      int j = fb >> 2, kk = fb & 3;
      int col = j*16 + lr, k = kk*32 + lg*8 + t;
      if (col < 128)       v = W1[((size_t)agent*128 + k)*128 + col];
      else if (col < 160)  v = Wc1[k*32 + (col-128)];
      else if (col == 160) v = Ws1[k];
    } else if (fb < FB_L1 + FB_L2) {
      int f = fb - FB_L1;
      int j = f >> 2, kk = f & 3;
      int col = j*16 + lr, k = kk*32 + lg*8 + t;
      v = W2[((size_t)agent*128 + k)*128 + col];
    } else {
      int f = fb - FB_L1 - FB_L2;
      int j = f >> 2, kk = f & 3;
      int col = j*16 + lr, k = kk*32 + lg*8 + t;
      v = W3[((size_t)agent*128 + k)*64 + col];
    }
    wbuf[tid] = f2bf(v);
  }
  if (tid < NAG * 176) {     // extended layer-1 bias: [b1 | bc1 | bs1 | 0]
    int agent = tid / 176, col = tid % 176;
    float v = 0.0f;
    if (col < 128)       v = b1[agent*128 + col];
    else if (col < 160)  v = bc1[col - 128];
    else if (col == 160) v = bs1[0];
    b1e[tid] = v;
  }
}

// ---------------- main: persistent per-agent weights, ZERO main-loop barriers ----------------
// 256 blocks (1/CU) x 512 threads (8 waves). Block b owns agent (b>>5) permanently and
// rows [(b&31)*1024, +1024). Agent's full 92KB fragment set staged to LDS ONCE in the
// prologue; main loop = 8 iterations of 128 rows (16/wave) with NO barriers, NO staging,
// NO drains — waves run fully decoupled (h per-wave; weights read-only). Biases/gate
// scalars loop-invariant. 8 agent contributions combine via atomicAdd into memset-zeroed
// out (commutative; fp32 order-noise ~1e-6, far under the bf16 absmax already carried).
__global__ void __launch_bounds__(512, 1)
qatten_main(const float* __restrict__ states,
            const float* __restrict__ b2g, const float* __restrict__ b3g,
            const float* __restrict__ ws2p, const float* __restrict__ bs2p,
            const float* __restrict__ wc2g, const float* __restrict__ bc2p,
            const unsigned short* __restrict__ wbuf,
            const float* __restrict__ b1e,
            float* __restrict__ out)
{
  __shared__ __align__(16) unsigned short wlds[FB_TOT*512];  // 92 KB: this agent's fragments
  __shared__ __align__(16) unsigned short hlds[8 * 2048];    // 32 KB: per-wave h buffers

  const int tid  = threadIdx.x;
  const int wave = tid >> 6;
  const int lane = tid & 63;
  const int lr   = lane & 15;
  const int lg   = lane >> 4;
  const int agent   = blockIdx.x >> 5;
  const int rowbase = (blockIdx.x & 31) << 10;   // 1024 rows per block

  unsigned short* hp = hlds + wave * 2048;   // this wave's 4KB h region

  // ---- prologue: stage this agent's full weight set (once) ----
  {
    const char* wag = (const char*)(wbuf + (size_t)agent * WAGENT);
    for (int c = wave; c < FB_TOT; c += 8)
      gload_lds16(wag + c*1024 + lane*16, (char*)wlds + c*1024);
  }

  // ---- loop-invariant biases & scalars ----
  float b1v[NJ1], b2v[NJ2], b3v[NJ3];
#pragma unroll
  for (int j = 0; j < NJ1; ++j) b1v[j] = b1e[agent*176 + j*16 + lr];
#pragma unroll
  for (int j = 0; j < NJ2; ++j) b2v[j] = b2g[agent*HDIM + j*16 + lr];
#pragma unroll
  for (int j = 0; j < NJ3; ++j) b3v[j] = b3g[agent*ADIM + j*16 + lr];
  const float ws2  = ws2p[0];
  const float bs2v = bs2p[0];
  const float bc2v = bc2p[0];
  const float wc2a = wc2g[lr];
  const float wc2b = wc2g[16 + lr];

  const f32x4 zero4 = {0.f, 0.f, 0.f, 0.f};

  // ---- prefetch iteration-0 states ----
  f32x4 sreg[8];
  {
    const float* sb = states + ((size_t)agent * BATCH + rowbase + wave*16) * DDIM;
#pragma unroll
    for (int kk = 0; kk < 4; ++kk) {
      const float* p = sb + lr*DDIM + kk*32 + lg*8;
      sreg[kk*2]   = *(const f32x4*)p;
      sreg[kk*2+1] = *(const f32x4*)(p + 4);
    }
  }

  __syncthreads();   // the ONLY barrier: weights published (drains prologue gloads)

  for (int it = 0; it < 8; ++it) {
    const int row0 = rowbase + it*128 + wave*16;

    // ---- convert prefetched states -> A1 fragments (pure VALU) ----
    bf16x8 afr[4];
#pragma unroll
    for (int kk = 0; kk < 4; ++kk) {
      f32x4 v0 = sreg[kk*2], v1 = sreg[kk*2+1];
      u32x4 w;
      w[0] = cvt_pk_bf16(v0[0], v0[1]);
      w[1] = cvt_pk_bf16(v0[2], v0[3]);
      w[2] = cvt_pk_bf16(v1[0], v1[1]);
      w[3] = cvt_pk_bf16(v1[2], v1[3]);
      afr[kk] = __builtin_bit_cast(bf16x8, w);
    }

    // ---- issue next iteration's states loads (land under this iteration) ----
    if (it < 7) {
      const float* sb = states + ((size_t)agent * BATCH + row0 + 128) * DDIM;
#pragma unroll
      for (int kk = 0; kk < 4; ++kk) {
        const float* p = sb + lr*DDIM + kk*32 + lg*8;
        sreg[kk*2]   = *(const f32x4*)p;
        sreg[kk*2+1] = *(const f32x4*)(p + 4);
      }
    }

    // ---- phase 1: L1 (j=0..7) + gates (j=8..10), 3-deep pipelined ----
    f32x4 eacc[3];
    {
      bf16x8 pf[3][4];
#pragma unroll
      for (int kk = 0; kk < 4; ++kk) {
        pf[0][kk] = *(const bf16x8*)&wlds[(0*4 + kk)*512 + lane*8];
        pf[1][kk] = *(const bf16x8*)&wlds[(1*4 + kk)*512 + lane*8];
      }
#pragma unroll
      for (int j = 0; j < 11; ++j) {
        if (j + 2 <= 10) {
#pragma unroll
          for (int kk = 0; kk < 4; ++kk)
            pf[(j+2)%3][kk] = *(const bf16x8*)&wlds[((j+2)*4 + kk)*512 + lane*8];
        }
        f32x4 acc = zero4;
#pragma unroll
        for (int kk = 0; kk < 4; ++kk)
          acc = __builtin_amdgcn_mfma_f32_16x16x32_bf16(afr[kk], pf[j%3][kk], acc, 0, 0, 0);
        if (j < 8) {
#pragma unroll
          for (int r = 0; r < 4; ++r) {
            float hv = acc[r] + b1v[j];
            hv = hv > 0.f ? hv : 0.f;
            int row = lg*4 + r;
            int bo = row*256 + (((j*16 + lr)*2) ^ ((row & 7) << 4));   // XOR swizzle
            *(unsigned short*)((char*)hp + bo) = f2bf1(hv);
          }
        } else {
          eacc[j-8] = acc;
        }
      }
    }

    // ---- gate & constraint scalars ----
    float scl[4], crow[4];
#pragma unroll
    for (int r = 0; r < 4; ++r) {
      float c0 = eacc[0][r] + b1v[8];  c0 = c0 > 0.f ? c0 : 0.f;
      float c1 = eacc[1][r] + b1v[9];  c1 = c1 > 0.f ? c1 : 0.f;
      float cd = c0*wc2a + c1*wc2b;
      cd += __shfl_xor(cd, 1);
      cd += __shfl_xor(cd, 2);
      cd += __shfl_xor(cd, 4);
      cd += __shfl_xor(cd, 8);          // sum over 16 cols within lg-group
      crow[r] = cd + bc2v;
      float sp = eacc[2][r] + b1v[10];
      sp = __shfl(sp, lane & 48);       // broadcast col-160 (lr==0) value
      sp = sp > 0.f ? sp : 0.f;
      float s = ws2 * sp + bs2v;
      scl[r] = 1.f / (1.f + __expf(-s));
    }

    // ---- A2 fragments from own h region (own-wave DS in-order; no fence needed) ----
#pragma unroll
    for (int kk = 0; kk < 4; ++kk) {
      int row = lr;
      int bo = row*256 + ((kk*64 + lg*16) ^ ((row & 7) << 4));
      afr[kk] = *(const bf16x8*)((char*)hp + bo);
    }

    // ---- phase 2: L2 (j=0..7), 3-deep pipelined ----
    {
      bf16x8 pf[3][4];
#pragma unroll
      for (int kk = 0; kk < 4; ++kk) {
        pf[0][kk] = *(const bf16x8*)&wlds[(FB_L1 + 0*4 + kk)*512 + lane*8];
        pf[1][kk] = *(const bf16x8*)&wlds[(FB_L1 + 1*4 + kk)*512 + lane*8];
      }
#pragma unroll
      for (int j = 0; j < 8; ++j) {
        if (j + 2 <= 7) {
#pragma unroll
          for (int kk = 0; kk < 4; ++kk)
            pf[(j+2)%3][kk] = *(const bf16x8*)&wlds[(FB_L1 + (j+2)*4 + kk)*512 + lane*8];
        }
        f32x4 acc = zero4;
#pragma unroll
        for (int kk = 0; kk < 4; ++kk)
          acc = __builtin_amdgcn_mfma_f32_16x16x32_bf16(afr[kk], pf[j%3][kk], acc, 0, 0, 0);
#pragma unroll
        for (int r = 0; r < 4; ++r) {
          float hv = acc[r] + b2v[j];
          hv = hv > 0.f ? hv : 0.f;
          int row = lg*4 + r;
          int bo = row*256 + (((j*16 + lr)*2) ^ ((row & 7) << 4));
          *(unsigned short*)((char*)hp + bo) = f2bf1(hv);   // overwrite h1 (A2 in regs)
        }
      }
    }

    // ---- A3 fragments from h2 (own-wave DS in-order) ----
#pragma unroll
    for (int kk = 0; kk < 4; ++kk) {
      int row = lr;
      int bo = row*256 + ((kk*64 + lg*16) ^ ((row & 7) << 4));
      afr[kk] = *(const bf16x8*)((char*)hp + bo);
    }

    // ---- phase 3: L3 (j=0..3), 2-deep; gated contribution -> atomicAdd ----
    {
      bf16x8 pf[2][4];
#pragma unroll
      for (int kk = 0; kk < 4; ++kk)
        pf[0][kk] = *(const bf16x8*)&wlds[(FB_L1 + FB_L2 + kk)*512 + lane*8];
#pragma unroll
      for (int j = 0; j < NJ3; ++j) {
        if (j < NJ3-1) {
#pragma unroll
          for (int kk = 0; kk < 4; ++kk)
            pf[(j+1)&1][kk] = *(const bf16x8*)&wlds[(FB_L1 + FB_L2 + (j+1)*4 + kk)*512 + lane*8];
        }
        f32x4 acc = zero4;
#pragma unroll
        for (int kk = 0; kk < 4; ++kk)
          acc = __builtin_amdgcn_mfma_f32_16x16x32_bf16(afr[kk], pf[j&1][kk], acc, 0, 0, 0);
#pragma unroll
        for (int r = 0; r < 4; ++r) {
          float v = (scl[r] * (acc[r] + b3v[j]) + crow[r]) * 0.125f;
          size_t row = (size_t)row0 + lg*4 + r;
          atomicAdd(&out[row*ADIM + j*16 + lr], v);
        }
      }
    }
  }
}

extern "C" void kernel_launch(void* const* d_in, const int* in_sizes, int n_in,
                              void* d_out, int out_size, void* d_ws, size_t ws_size,
                              hipStream_t stream)
{
  const float* states = (const float*)d_in[0];
  const float* W1  = (const float*)d_in[1];
  const float* b1  = (const float*)d_in[2];
  const float* W2  = (const float*)d_in[3];
  const float* b2  = (const float*)d_in[4];
  const float* W3  = (const float*)d_in[5];
  const float* b3  = (const float*)d_in[6];
  const float* Ws1 = (const float*)d_in[13];
  const float* bs1 = (const float*)d_in[14];
  const float* Ws2 = (const float*)d_in[15];
  const float* bs2 = (const float*)d_in[16];
  const float* Wc1 = (const float*)d_in[17];
  const float* bc1 = (const float*)d_in[18];
  const float* Wc2 = (const float*)d_in[19];
  const float* bc2 = (const float*)d_in[20];

  unsigned short* wbuf = (unsigned short*)d_ws;
  float* b1e = (float*)((char*)d_ws + (size_t)NAG * WAGENT * 2);

  hipMemsetAsync(d_out, 0, (size_t)out_size * sizeof(float), stream);

  dim3 pb(256), pg((NAG * WAGENT + 255) / 256);
  prep_weights<<<pg, pb, 0, stream>>>(W1, W2, W3, Wc1, Ws1, b1, bc1, bs1, wbuf, b1e);

  dim3 mb(512), mg(NAG * 32);   // 256 blocks = 1/CU: block b -> agent b>>5, rows (b&31)*1024
  qatten_main<<<mg, mb, 0, stream>>>(states, b2, b3, Ws2, bs2, Wc2, bc2,
                                     wbuf, b1e, (float*)d_out);
}